// Round 15
// baseline (60.197 us; speedup 1.0000x reference)
//
#include <hip/hip_runtime.h>
#include <math.h>

#define BB 2
#define SS 192
#define DD 512
#define HH 8
#define HD 64
#define QCB 6                 // q-rows per block
#define NQC (SS / QCB)        // 32 q-chunks
#define PROJ_N (BB*HH*SS*HD)
#define SCL (0.125f * 1.44269504088896f)   // 1/sqrt(64) * log2(e)

typedef __attribute__((ext_vector_type(4))) float f32x4;
typedef _Float16 f16x8 __attribute__((ext_vector_type(8)));

// 8 f32 -> f16x8, RNE (v_cvt_f16_f32)
__device__ __forceinline__ f16x8 cvt8_f16_rne(const float* g) {
    f16x8 r;
#pragma unroll
    for (int i = 0; i < 8; ++i) r[i] = (_Float16)g[i];
    return r;
}

// Fast exp2 on the full-rate VALU (v_exp_f32 is ~32 cyc/wave64; this is ~9
// VALU ops ~ 18 cyc). n = round(x) via RNE magic add; f = x-n in [-0.5,0.5];
// degree-4 Taylor (rel err ~4e-5); scale by 2^n via integer exponent add.
// Valid for |x| < ~120 (scores here are O(10)).
__device__ __forceinline__ float poly_exp2(float x) {
    const float magic = 12582912.0f;              // 1.5 * 2^23
    const float t = x + magic;
    const int n = __float_as_int(t) - 0x4B400000;
    const float f = x - (t - magic);
    float p = fmaf(f, 0.0096180f, 0.0555041f);
    p = fmaf(f, p, 0.2402265f);
    p = fmaf(f, p, 0.6931472f);
    p = fmaf(f, p, 1.0f);
    return __int_as_float(__float_as_int(p) + (n << 23));
}

// ---------------------------------------------------------------------------
// Single-f16 MFMA GEMM: y = x @ W^T  (x: M x 512, W: 512 x 512, f32 in).
// 64x64 tile / block, 256 thr (4 waves, 2x2), BK=32, double-buffered LDS.
// ---------------------------------------------------------------------------
template <int SPLIT>
__device__ __forceinline__ void gemm_mfma_body(const float* __restrict__ x,
                                               const float* __restrict__ W,
                                               float* __restrict__ y) {
    __shared__ short Ahs[2][4 * 64 * 8];   // [buf][kchunk][row][8] f16: 8 KB
    __shared__ short Bhs[2][4 * 64 * 8];

    const int t = threadIdx.x;
    const int lane = t & 63, w = t >> 6;
    const int wr = w >> 1, wc = w & 1;
    const int c16 = lane & 15, q4 = lane >> 4;
    const int m0 = blockIdx.x * 64, n0 = blockIdx.y * 64;
    const int sr = t >> 2, scc = t & 3;

    f32x4 acc[2][2];
#pragma unroll
    for (int a = 0; a < 2; ++a)
#pragma unroll
        for (int b = 0; b < 2; ++b) acc[a][b] = (f32x4){0.f, 0.f, 0.f, 0.f};

#define STAGE(kk, bf)                                                              \
    {                                                                              \
        float a8[8], w8[8];                                                        \
        *(f32x4*)&a8[0] = *(const f32x4*)&x[(m0 + sr) * 512 + (kk) + scc * 8];     \
        *(f32x4*)&a8[4] = *(const f32x4*)&x[(m0 + sr) * 512 + (kk) + scc * 8 + 4]; \
        *(f32x4*)&w8[0] = *(const f32x4*)&W[(n0 + sr) * 512 + (kk) + scc * 8];     \
        *(f32x4*)&w8[4] = *(const f32x4*)&W[(n0 + sr) * 512 + (kk) + scc * 8 + 4]; \
        *(f16x8*)&Ahs[bf][(scc * 64 + sr) * 8] = cvt8_f16_rne(a8);                 \
        *(f16x8*)&Bhs[bf][(scc * 64 + sr) * 8] = cvt8_f16_rne(w8);                 \
    }

    STAGE(0, 0)
    for (int s = 0; s < 16; ++s) {
        __syncthreads();
        if (s + 1 < 16) STAGE((s + 1) * 32, (s + 1) & 1)
        const int b = s & 1;
        f16x8 aH[2], bH[2];
#pragma unroll
        for (int mt = 0; mt < 2; ++mt) {
            const int row = wr * 32 + mt * 16 + c16;
            aH[mt] = *(const f16x8*)&Ahs[b][(q4 * 64 + row) * 8];
        }
#pragma unroll
        for (int nt = 0; nt < 2; ++nt) {
            const int col = wc * 32 + nt * 16 + c16;
            bH[nt] = *(const f16x8*)&Bhs[b][(q4 * 64 + col) * 8];
        }
#pragma unroll
        for (int mt = 0; mt < 2; ++mt)
#pragma unroll
            for (int nt = 0; nt < 2; ++nt)
                acc[mt][nt] = __builtin_amdgcn_mfma_f32_16x16x32_f16(aH[mt], bH[nt], acc[mt][nt], 0, 0, 0);
    }
#undef STAGE

#pragma unroll
    for (int mt = 0; mt < 2; ++mt)
#pragma unroll
        for (int nt = 0; nt < 2; ++nt)
#pragma unroll
            for (int j = 0; j < 4; ++j) {
                const int n_row = m0 + wr * 32 + mt * 16 + q4 * 4 + j;
                const int col = n0 + wc * 32 + nt * 16 + c16;
                const float v = acc[mt][nt][j];
                if (SPLIT) {
                    const int b = n_row / SS, s2 = n_row % SS;
                    const int h = col >> 6, e = col & 63;
                    y[((b * HH + h) * SS + s2) * HD + e] = v;
                } else {
                    y[n_row * 512 + col] = v;
                }
            }
}

__global__ __launch_bounds__(256) void proj4_kernel(
    const float* __restrict__ xq, const float* __restrict__ xk,
    const float* __restrict__ xl, const float* __restrict__ xv,
    const float* __restrict__ Wq, const float* __restrict__ Wk,
    const float* __restrict__ Wv, float* __restrict__ ws) {
    const int p = blockIdx.z;
    const float* x = (p == 0) ? xq : (p == 1) ? xk : (p == 2) ? xl : xv;
    const float* W = (p == 0) ? Wq : (p == 3) ? Wv : Wk;
    gemm_mfma_body<1>(x, W, ws + p * PROJ_N);
}

__global__ __launch_bounds__(256) void outproj_kernel(
    const float* __restrict__ att, const float* __restrict__ Wout,
    float* __restrict__ out) {
    gemm_mfma_body<0>(att, Wout, out);
}

// ---------------------------------------------------------------------------
// MFMA rank-3 attention (R13 structure + poly exp2).
// Grid 512 = 16 bh x 32 qc (QCB=6) = 2 blocks/CU. 512 thr = 8 waves
// (2 lg x 4 kg); wave covers 96 l x 48 k. K,L f16 frag-major in LDS;
// B hoisted per q; 3 independent shuffle chains per q. The binding
// resource was v_exp_f32 (~32 cyc/wave64, 23 us floor for 113M exps);
// poly_exp2 moves it to the full-rate VALU at ~18 cyc.
// ---------------------------------------------------------------------------
__global__ __launch_bounds__(512, 4) void attn3d_mfma_kernel(
    const float* __restrict__ qh, const float* __restrict__ kh,
    const float* __restrict__ lh, const float* __restrict__ vh,
    float* __restrict__ att) {
    __shared__ short Kf16[8][193][8];       // [ec][k(+pad)][8] f16: 24.7 KB
    __shared__ short Lf16[8][193][8];       // [ec][l(+pad)][8] f16: 24.7 KB
    __shared__ short qpk[QCB][8][8];        // [q][ec][8] f16: 768 B
    __shared__ float partial[2][QCB][196];  // [lg][q][k(+pad)]: 9.4 KB
    __shared__ float Wt[QCB][192];          // 4.6 KB
    __shared__ float zinv[QCB];

    const int blk = blockIdx.x;
    const int bh = blk >> 5, qc = blk & 31;
    const int t = threadIdx.x;
    const int lane = t & 63, w = t >> 6;
    const int lg = w >> 2, kg = w & 3;
    const int c = lane & 15, eh = lane >> 4;

    // ---- stage q rows as f16 (scale+log2e folded) ----
    if (t < QCB * 64) {
        const int q = t >> 6, e = t & 63;
        const float v = qh[(bh * SS + qc * QCB + q) * HD + e] * SCL;
        qpk[q][e >> 3][e & 7] = __builtin_bit_cast(short, (_Float16)v);
    }
    // ---- stage K and L as f16 frag-major ----
#pragma unroll
    for (int j = 0; j < 3; ++j) {
        const int cid = t + 512 * j;          // 1536 8-elem chunks each
        const int k = cid >> 3, ec = cid & 7;
        float b8[8];
        const float* kp = &kh[(bh * SS + k) * HD + ec * 8];
        *(f32x4*)&b8[0] = *(const f32x4*)&kp[0];
        *(f32x4*)&b8[4] = *(const f32x4*)&kp[4];
        *(f16x8*)&Kf16[ec][k][0] = cvt8_f16_rne(b8);
        const float* lp = &lh[(bh * SS + k) * HD + ec * 8];
        *(f32x4*)&b8[0] = *(const f32x4*)&lp[0];
        *(f32x4*)&b8[4] = *(const f32x4*)&lp[4];
        *(f16x8*)&Lf16[ec][k][0] = cvt8_f16_rne(b8);
    }
    __syncthreads();   // qpk, Kf16, Lf16 ready

    // ---- runtime q loop; B hoisted per q; no cross-q register state ----
    for (int q = 0; q < QCB; ++q) {
        const f16x8 qf0 = *(const f16x8*)&qpk[q][eh][0];
        const f16x8 qf1 = *(const f16x8*)&qpk[q][4 + eh][0];
        f16x8 Bf[3][2];
#pragma unroll
        for (int kt = 0; kt < 3; ++kt) {
            const int col = kg * 48 + kt * 16 + c;
            Bf[kt][0] = *(const f16x8*)&Kf16[eh][col][0] * qf0;
            Bf[kt][1] = *(const f16x8*)&Kf16[4 + eh][col][0] * qf1;
        }
        float rr0 = 0.f, rr1 = 0.f, rr2 = 0.f;
#pragma unroll
        for (int lt = 0; lt < 6; ++lt) {
            const int row = lg * 96 + lt * 16 + c;
            const f16x8 A0 = *(const f16x8*)&Lf16[eh][row][0];
            const f16x8 A1 = *(const f16x8*)&Lf16[4 + eh][row][0];
            f32x4 a0 = (f32x4){0.f, 0.f, 0.f, 0.f};
            f32x4 a1 = (f32x4){0.f, 0.f, 0.f, 0.f};
            f32x4 a2 = (f32x4){0.f, 0.f, 0.f, 0.f};
            a0 = __builtin_amdgcn_mfma_f32_16x16x32_f16(A0, Bf[0][0], a0, 0, 0, 0);
            a1 = __builtin_amdgcn_mfma_f32_16x16x32_f16(A0, Bf[1][0], a1, 0, 0, 0);
            a2 = __builtin_amdgcn_mfma_f32_16x16x32_f16(A0, Bf[2][0], a2, 0, 0, 0);
            a0 = __builtin_amdgcn_mfma_f32_16x16x32_f16(A1, Bf[0][1], a0, 0, 0, 0);
            a1 = __builtin_amdgcn_mfma_f32_16x16x32_f16(A1, Bf[1][1], a1, 0, 0, 0);
            a2 = __builtin_amdgcn_mfma_f32_16x16x32_f16(A1, Bf[2][1], a2, 0, 0, 0);
            rr0 += (poly_exp2(a0[0]) + poly_exp2(a0[1])) +
                   (poly_exp2(a0[2]) + poly_exp2(a0[3]));
            rr1 += (poly_exp2(a1[0]) + poly_exp2(a1[1])) +
                   (poly_exp2(a1[2]) + poly_exp2(a1[3]));
            rr2 += (poly_exp2(a2[0]) + poly_exp2(a2[1])) +
                   (poly_exp2(a2[2]) + poly_exp2(a2[3]));
        }
        // 3 independent shuffle chains (ILP-overlapped)
        rr0 += __shfl_xor(rr0, 16, 64);
        rr1 += __shfl_xor(rr1, 16, 64);
        rr2 += __shfl_xor(rr2, 16, 64);
        rr0 += __shfl_xor(rr0, 32, 64);
        rr1 += __shfl_xor(rr1, 32, 64);
        rr2 += __shfl_xor(rr2, 32, 64);
        if (eh == 0) {
            partial[lg][q][kg * 48 + 0 * 16 + c] = rr0;
            partial[lg][q][kg * 48 + 1 * 16 + c] = rr1;
            partial[lg][q][kg * 48 + 2 * 16 + c] = rr2;
        }
    }
    __syncthreads();   // all partials written

    // combine lg partials
    for (int id = t; id < QCB * 192; id += 512) {
        const int q = id / 192, k = id - q * 192;
        Wt[q][k] = partial[0][q][k] + partial[1][q][k];
    }
    __syncthreads();

    // Z per q (wave w handles q = w)
    if (w < QCB) {
        const int q = w;
        float z = Wt[q][lane] + Wt[q][lane + 64] + Wt[q][lane + 128];
#pragma unroll
        for (int off = 32; off >= 1; off >>= 1) z += __shfl_xor(z, off, 64);
        if (lane == 0) zinv[q] = 1.f / z;
    }
    __syncthreads();

    // attended: att[q,d] = zinv * sum_k Wt[q][k] * vh[k,d]; 8 loads in flight
    const int b = bh >> 3, h = bh & 7;
    if (t < QCB * 64) {
        const int q = t >> 6, d = t & 63;
        const float* vp = vh + bh * SS * HD + d;
        float sum = 0.f;
        for (int k0 = 0; k0 < SS; k0 += 8) {
            float v8[8];
#pragma unroll
            for (int j = 0; j < 8; ++j) v8[j] = vp[(k0 + j) * HD];
#pragma unroll
            for (int j = 0; j < 8; ++j) sum = fmaf(Wt[q][k0 + j], v8[j], sum);
        }
        att[(b * SS + qc * QCB + q) * DD + h * HD + d] = sum * zinv[q];
    }
}

extern "C" void kernel_launch(void* const* d_in, const int* in_sizes, int n_in,
                              void* d_out, int out_size, void* d_ws, size_t ws_size,
                              hipStream_t stream) {
    (void)in_sizes; (void)n_in; (void)out_size; (void)ws_size;
    const float* q    = (const float*)d_in[0];
    const float* k    = (const float*)d_in[1];
    const float* l    = (const float*)d_in[2];
    const float* v    = (const float*)d_in[3];
    const float* Wq   = (const float*)d_in[4];
    const float* Wk   = (const float*)d_in[5];
    const float* Wv   = (const float*)d_in[6];
    const float* Wout = (const float*)d_in[7];
    float* out = (float*)d_out;

    float* ws  = (float*)d_ws;
    float* qhp = ws + 0 * PROJ_N;
    float* khp = ws + 1 * PROJ_N;
    float* lhp = ws + 2 * PROJ_N;
    float* vhp = ws + 3 * PROJ_N;
    float* atp = ws + 4 * PROJ_N;

    proj4_kernel<<<dim3(384 / 64, 512 / 64, 4), 256, 0, stream>>>(
        q, k, l, v, Wq, Wk, Wv, ws);
    attn3d_mfma_kernel<<<dim3(16 * NQC), 512, 0, stream>>>(qhp, khp, lhp, vhp, atp);
    outproj_kernel<<<dim3(384 / 64, 512 / 64), 256, 0, stream>>>(atp, Wout, out);
}

// Round 16
// 49.880 us; speedup vs baseline: 1.2068x; 1.2068x over previous
//
#include <hip/hip_runtime.h>
#include <math.h>

#define BB 2
#define SS 192
#define DD 512
#define HH 8
#define HD 64
#define QCB 6                 // q-rows per block
#define NQC (SS / QCB)        // 32 q-chunks
#define PROJ_N (BB*HH*SS*HD)
#define SCL (0.125f * 1.44269504088896f)   // 1/sqrt(64) * log2(e)

typedef __attribute__((ext_vector_type(4))) float f32x4;
typedef _Float16 f16x8 __attribute__((ext_vector_type(8)));

// 8 f32 -> f16x8, RNE (v_cvt_f16_f32)
__device__ __forceinline__ f16x8 cvt8_f16_rne(const float* g) {
    f16x8 r;
#pragma unroll
    for (int i = 0; i < 8; ++i) r[i] = (_Float16)g[i];
    return r;
}

// ---------------------------------------------------------------------------
// Single-f16 MFMA GEMM: y = x @ W^T  (x: M x 512, W: 512 x 512, f32 in).
// 64x64 tile / block, 256 thr (4 waves, 2x2), BK=32, double-buffered LDS.
// ---------------------------------------------------------------------------
template <int SPLIT>
__device__ __forceinline__ void gemm_mfma_body(const float* __restrict__ x,
                                               const float* __restrict__ W,
                                               float* __restrict__ y) {
    __shared__ short Ahs[2][4 * 64 * 8];   // [buf][kchunk][row][8] f16: 8 KB
    __shared__ short Bhs[2][4 * 64 * 8];

    const int t = threadIdx.x;
    const int lane = t & 63, w = t >> 6;
    const int wr = w >> 1, wc = w & 1;
    const int c16 = lane & 15, q4 = lane >> 4;
    const int m0 = blockIdx.x * 64, n0 = blockIdx.y * 64;
    const int sr = t >> 2, scc = t & 3;

    f32x4 acc[2][2];
#pragma unroll
    for (int a = 0; a < 2; ++a)
#pragma unroll
        for (int b = 0; b < 2; ++b) acc[a][b] = (f32x4){0.f, 0.f, 0.f, 0.f};

#define STAGE(kk, bf)                                                              \
    {                                                                              \
        float a8[8], w8[8];                                                        \
        *(f32x4*)&a8[0] = *(const f32x4*)&x[(m0 + sr) * 512 + (kk) + scc * 8];     \
        *(f32x4*)&a8[4] = *(const f32x4*)&x[(m0 + sr) * 512 + (kk) + scc * 8 + 4]; \
        *(f32x4*)&w8[0] = *(const f32x4*)&W[(n0 + sr) * 512 + (kk) + scc * 8];     \
        *(f32x4*)&w8[4] = *(const f32x4*)&W[(n0 + sr) * 512 + (kk) + scc * 8 + 4]; \
        *(f16x8*)&Ahs[bf][(scc * 64 + sr) * 8] = cvt8_f16_rne(a8);                 \
        *(f16x8*)&Bhs[bf][(scc * 64 + sr) * 8] = cvt8_f16_rne(w8);                 \
    }

    STAGE(0, 0)
    for (int s = 0; s < 16; ++s) {
        __syncthreads();
        if (s + 1 < 16) STAGE((s + 1) * 32, (s + 1) & 1)
        const int b = s & 1;
        f16x8 aH[2], bH[2];
#pragma unroll
        for (int mt = 0; mt < 2; ++mt) {
            const int row = wr * 32 + mt * 16 + c16;
            aH[mt] = *(const f16x8*)&Ahs[b][(q4 * 64 + row) * 8];
        }
#pragma unroll
        for (int nt = 0; nt < 2; ++nt) {
            const int col = wc * 32 + nt * 16 + c16;
            bH[nt] = *(const f16x8*)&Bhs[b][(q4 * 64 + col) * 8];
        }
#pragma unroll
        for (int mt = 0; mt < 2; ++mt)
#pragma unroll
            for (int nt = 0; nt < 2; ++nt)
                acc[mt][nt] = __builtin_amdgcn_mfma_f32_16x16x32_f16(aH[mt], bH[nt], acc[mt][nt], 0, 0, 0);
    }
#undef STAGE

#pragma unroll
    for (int mt = 0; mt < 2; ++mt)
#pragma unroll
        for (int nt = 0; nt < 2; ++nt)
#pragma unroll
            for (int j = 0; j < 4; ++j) {
                const int n_row = m0 + wr * 32 + mt * 16 + q4 * 4 + j;
                const int col = n0 + wc * 32 + nt * 16 + c16;
                const float v = acc[mt][nt][j];
                if (SPLIT) {
                    const int b = n_row / SS, s2 = n_row % SS;
                    const int h = col >> 6, e = col & 63;
                    y[((b * HH + h) * SS + s2) * HD + e] = v;
                } else {
                    y[n_row * 512 + col] = v;
                }
            }
}

__global__ __launch_bounds__(256) void proj4_kernel(
    const float* __restrict__ xq, const float* __restrict__ xk,
    const float* __restrict__ xl, const float* __restrict__ xv,
    const float* __restrict__ Wq, const float* __restrict__ Wk,
    const float* __restrict__ Wv, float* __restrict__ ws) {
    const int p = blockIdx.z;
    const float* x = (p == 0) ? xq : (p == 1) ? xk : (p == 2) ? xl : xv;
    const float* W = (p == 0) ? Wq : (p == 3) ? Wv : Wk;
    gemm_mfma_body<1>(x, W, ws + p * PROJ_N);
}

__global__ __launch_bounds__(256) void outproj_kernel(
    const float* __restrict__ att, const float* __restrict__ Wout,
    float* __restrict__ out) {
    gemm_mfma_body<0>(att, Wout, out);
}

// ---------------------------------------------------------------------------
// MFMA rank-3 attention (R13 structure + per-wave q-phase rotation).
// Grid 512 = 16 bh x 32 qc (QCB=6) = 2 blocks/CU. 512 thr = 8 waves
// (2 lg x 4 kg); wave covers 96 l x 48 k. K,L f16 frag-major in LDS;
// B hoisted per q; 3 independent shuffle chains per q; v_exp_f32 (trans
// pipe, parallel to VALU -- poly-exp on VALU was 10us SLOWER, R15).
// Waves iterate q in rotated order (q = (qi + w) % 6) so DS/exp/MFMA
// bursts desynchronize across the 16 resident waves per CU.
// ---------------------------------------------------------------------------
__global__ __launch_bounds__(512, 4) void attn3d_mfma_kernel(
    const float* __restrict__ qh, const float* __restrict__ kh,
    const float* __restrict__ lh, const float* __restrict__ vh,
    float* __restrict__ att) {
    __shared__ short Kf16[8][193][8];       // [ec][k(+pad)][8] f16: 24.7 KB
    __shared__ short Lf16[8][193][8];       // [ec][l(+pad)][8] f16: 24.7 KB
    __shared__ short qpk[QCB][8][8];        // [q][ec][8] f16: 768 B
    __shared__ float partial[2][QCB][196];  // [lg][q][k(+pad)]: 9.4 KB
    __shared__ float Wt[QCB][192];          // 4.6 KB
    __shared__ float zinv[QCB];

    const int blk = blockIdx.x;
    const int bh = blk >> 5, qc = blk & 31;
    const int t = threadIdx.x;
    const int lane = t & 63, w = t >> 6;
    const int lg = w >> 2, kg = w & 3;
    const int c = lane & 15, eh = lane >> 4;

    // ---- stage q rows as f16 (scale+log2e folded) ----
    if (t < QCB * 64) {
        const int q = t >> 6, e = t & 63;
        const float v = qh[(bh * SS + qc * QCB + q) * HD + e] * SCL;
        qpk[q][e >> 3][e & 7] = __builtin_bit_cast(short, (_Float16)v);
    }
    // ---- stage K and L as f16 frag-major ----
#pragma unroll
    for (int j = 0; j < 3; ++j) {
        const int cid = t + 512 * j;          // 1536 8-elem chunks each
        const int k = cid >> 3, ec = cid & 7;
        float b8[8];
        const float* kp = &kh[(bh * SS + k) * HD + ec * 8];
        *(f32x4*)&b8[0] = *(const f32x4*)&kp[0];
        *(f32x4*)&b8[4] = *(const f32x4*)&kp[4];
        *(f16x8*)&Kf16[ec][k][0] = cvt8_f16_rne(b8);
        const float* lp = &lh[(bh * SS + k) * HD + ec * 8];
        *(f32x4*)&b8[0] = *(const f32x4*)&lp[0];
        *(f32x4*)&b8[4] = *(const f32x4*)&lp[4];
        *(f16x8*)&Lf16[ec][k][0] = cvt8_f16_rne(b8);
    }
    __syncthreads();   // qpk, Kf16, Lf16 ready

    // ---- runtime q loop, per-wave rotated phase; B hoisted per q ----
    for (int qi = 0; qi < QCB; ++qi) {
        const int q = (qi + w) % QCB;       // desync waves' phases
        const f16x8 qf0 = *(const f16x8*)&qpk[q][eh][0];
        const f16x8 qf1 = *(const f16x8*)&qpk[q][4 + eh][0];
        f16x8 Bf[3][2];
#pragma unroll
        for (int kt = 0; kt < 3; ++kt) {
            const int col = kg * 48 + kt * 16 + c;
            Bf[kt][0] = *(const f16x8*)&Kf16[eh][col][0] * qf0;
            Bf[kt][1] = *(const f16x8*)&Kf16[4 + eh][col][0] * qf1;
        }
        float rr0 = 0.f, rr1 = 0.f, rr2 = 0.f;
#pragma unroll
        for (int lt = 0; lt < 6; ++lt) {
            const int row = lg * 96 + lt * 16 + c;
            const f16x8 A0 = *(const f16x8*)&Lf16[eh][row][0];
            const f16x8 A1 = *(const f16x8*)&Lf16[4 + eh][row][0];
            f32x4 a0 = (f32x4){0.f, 0.f, 0.f, 0.f};
            f32x4 a1 = (f32x4){0.f, 0.f, 0.f, 0.f};
            f32x4 a2 = (f32x4){0.f, 0.f, 0.f, 0.f};
            a0 = __builtin_amdgcn_mfma_f32_16x16x32_f16(A0, Bf[0][0], a0, 0, 0, 0);
            a1 = __builtin_amdgcn_mfma_f32_16x16x32_f16(A0, Bf[1][0], a1, 0, 0, 0);
            a2 = __builtin_amdgcn_mfma_f32_16x16x32_f16(A0, Bf[2][0], a2, 0, 0, 0);
            a0 = __builtin_amdgcn_mfma_f32_16x16x32_f16(A1, Bf[0][1], a0, 0, 0, 0);
            a1 = __builtin_amdgcn_mfma_f32_16x16x32_f16(A1, Bf[1][1], a1, 0, 0, 0);
            a2 = __builtin_amdgcn_mfma_f32_16x16x32_f16(A1, Bf[2][1], a2, 0, 0, 0);
            rr0 += (__builtin_amdgcn_exp2f(a0[0]) + __builtin_amdgcn_exp2f(a0[1])) +
                   (__builtin_amdgcn_exp2f(a0[2]) + __builtin_amdgcn_exp2f(a0[3]));
            rr1 += (__builtin_amdgcn_exp2f(a1[0]) + __builtin_amdgcn_exp2f(a1[1])) +
                   (__builtin_amdgcn_exp2f(a1[2]) + __builtin_amdgcn_exp2f(a1[3]));
            rr2 += (__builtin_amdgcn_exp2f(a2[0]) + __builtin_amdgcn_exp2f(a2[1])) +
                   (__builtin_amdgcn_exp2f(a2[2]) + __builtin_amdgcn_exp2f(a2[3]));
        }
        // 3 independent shuffle chains (ILP-overlapped)
        rr0 += __shfl_xor(rr0, 16, 64);
        rr1 += __shfl_xor(rr1, 16, 64);
        rr2 += __shfl_xor(rr2, 16, 64);
        rr0 += __shfl_xor(rr0, 32, 64);
        rr1 += __shfl_xor(rr1, 32, 64);
        rr2 += __shfl_xor(rr2, 32, 64);
        if (eh == 0) {
            partial[lg][q][kg * 48 + 0 * 16 + c] = rr0;
            partial[lg][q][kg * 48 + 1 * 16 + c] = rr1;
            partial[lg][q][kg * 48 + 2 * 16 + c] = rr2;
        }
    }
    __syncthreads();   // all partials written

    // combine lg partials
    for (int id = t; id < QCB * 192; id += 512) {
        const int q = id / 192, k = id - q * 192;
        Wt[q][k] = partial[0][q][k] + partial[1][q][k];
    }
    __syncthreads();

    // Z per q (wave w handles q = w)
    if (w < QCB) {
        const int q = w;
        float z = Wt[q][lane] + Wt[q][lane + 64] + Wt[q][lane + 128];
#pragma unroll
        for (int off = 32; off >= 1; off >>= 1) z += __shfl_xor(z, off, 64);
        if (lane == 0) zinv[q] = 1.f / z;
    }
    __syncthreads();

    // attended: att[q,d] = zinv * sum_k Wt[q][k] * vh[k,d]; 8 loads in flight
    const int b = bh >> 3, h = bh & 7;
    if (t < QCB * 64) {
        const int q = t >> 6, d = t & 63;
        const float* vp = vh + bh * SS * HD + d;
        float sum = 0.f;
        for (int k0 = 0; k0 < SS; k0 += 8) {
            float v8[8];
#pragma unroll
            for (int j = 0; j < 8; ++j) v8[j] = vp[(k0 + j) * HD];
#pragma unroll
            for (int j = 0; j < 8; ++j) sum = fmaf(Wt[q][k0 + j], v8[j], sum);
        }
        att[(b * SS + qc * QCB + q) * DD + h * HD + d] = sum * zinv[q];
    }
}

extern "C" void kernel_launch(void* const* d_in, const int* in_sizes, int n_in,
                              void* d_out, int out_size, void* d_ws, size_t ws_size,
                              hipStream_t stream) {
    (void)in_sizes; (void)n_in; (void)out_size; (void)ws_size;
    const float* q    = (const float*)d_in[0];
    const float* k    = (const float*)d_in[1];
    const float* l    = (const float*)d_in[2];
    const float* v    = (const float*)d_in[3];
    const float* Wq   = (const float*)d_in[4];
    const float* Wk   = (const float*)d_in[5];
    const float* Wv   = (const float*)d_in[6];
    const float* Wout = (const float*)d_in[7];
    float* out = (float*)d_out;

    float* ws  = (float*)d_ws;
    float* qhp = ws + 0 * PROJ_N;
    float* khp = ws + 1 * PROJ_N;
    float* lhp = ws + 2 * PROJ_N;
    float* vhp = ws + 3 * PROJ_N;
    float* atp = ws + 4 * PROJ_N;

    proj4_kernel<<<dim3(384 / 64, 512 / 64, 4), 256, 0, stream>>>(
        q, k, l, v, Wq, Wk, Wv, ws);
    attn3d_mfma_kernel<<<dim3(16 * NQC), 512, 0, stream>>>(qhp, khp, lhp, vhp, atp);
    outproj_kernel<<<dim3(384 / 64, 512 / 64), 256, 0, stream>>>(atp, Wout, out);
}

// Round 17
// 49.705 us; speedup vs baseline: 1.2111x; 1.0035x over previous
//
#include <hip/hip_runtime.h>
#include <math.h>

#define BB 2
#define SS 192
#define DD 512
#define HH 8
#define HD 64
#define QCB 6                 // q-rows per block
#define NQC (SS / QCB)        // 32 q-chunks
#define PROJ_N (BB*HH*SS*HD)
#define SCL (0.125f * 1.44269504088896f)   // 1/sqrt(64) * log2(e)

typedef __attribute__((ext_vector_type(4))) float f32x4;
typedef _Float16 f16x8 __attribute__((ext_vector_type(8)));

// 8 f32 -> f16x8, RNE (v_cvt_f16_f32)
__device__ __forceinline__ f16x8 cvt8_f16_rne(const float* g) {
    f16x8 r;
#pragma unroll
    for (int i = 0; i < 8; ++i) r[i] = (_Float16)g[i];
    return r;
}

// ---------------------------------------------------------------------------
// Zero init for atomic targets: ws proj region (4*PROJ_N f32) + out (384*512).
// ---------------------------------------------------------------------------
__global__ __launch_bounds__(256) void zero_kernel(float* __restrict__ wsp,
                                                   float* __restrict__ out) {
    const int i = blockIdx.x * 256 + threadIdx.x;
    if (i < 4 * PROJ_N) wsp[i] = 0.f;
    if (i < BB * SS * DD) out[i] = 0.f;
}

// ---------------------------------------------------------------------------
// Single-f16 MFMA projection GEMM, split-K x2 (atomicAdd epilogue).
// y[n,j] (+)= sum_{i in khalf} x[n,i] * W[j,i]; head-split scatter.
// 64x64 tile / block, 256 thr (4 waves, 2x2), BK=32, 8 rounds per half.
// ---------------------------------------------------------------------------
__global__ __launch_bounds__(256) void proj4_kernel(
    const float* __restrict__ xq, const float* __restrict__ xk,
    const float* __restrict__ xl, const float* __restrict__ xv,
    const float* __restrict__ Wq, const float* __restrict__ Wk,
    const float* __restrict__ Wv, float* __restrict__ ws) {
    const int z = blockIdx.z;            // 0..7: proj p = z>>1, K-half = z&1
    const int p = z >> 1;
    const int k0 = (z & 1) * 256;
    const float* x = (p == 0) ? xq : (p == 1) ? xk : (p == 2) ? xl : xv;
    const float* W = (p == 0) ? Wq : (p == 3) ? Wv : Wk;
    float* y = ws + p * PROJ_N;

    __shared__ short Ahs[2][4 * 64 * 8];   // [buf][kchunk][row][8] f16: 8 KB
    __shared__ short Bhs[2][4 * 64 * 8];

    const int t = threadIdx.x;
    const int lane = t & 63, w = t >> 6;
    const int wr = w >> 1, wc = w & 1;
    const int c16 = lane & 15, q4 = lane >> 4;
    const int m0 = blockIdx.x * 64, n0 = blockIdx.y * 64;
    const int sr = t >> 2, scc = t & 3;

    f32x4 acc[2][2];
#pragma unroll
    for (int a = 0; a < 2; ++a)
#pragma unroll
        for (int b = 0; b < 2; ++b) acc[a][b] = (f32x4){0.f, 0.f, 0.f, 0.f};

#define STAGE(kk, bf)                                                              \
    {                                                                              \
        float a8[8], w8[8];                                                        \
        *(f32x4*)&a8[0] = *(const f32x4*)&x[(m0 + sr) * 512 + (kk) + scc * 8];     \
        *(f32x4*)&a8[4] = *(const f32x4*)&x[(m0 + sr) * 512 + (kk) + scc * 8 + 4]; \
        *(f32x4*)&w8[0] = *(const f32x4*)&W[(n0 + sr) * 512 + (kk) + scc * 8];     \
        *(f32x4*)&w8[4] = *(const f32x4*)&W[(n0 + sr) * 512 + (kk) + scc * 8 + 4]; \
        *(f16x8*)&Ahs[bf][(scc * 64 + sr) * 8] = cvt8_f16_rne(a8);                 \
        *(f16x8*)&Bhs[bf][(scc * 64 + sr) * 8] = cvt8_f16_rne(w8);                 \
    }

    STAGE(k0, 0)
    for (int s = 0; s < 8; ++s) {
        __syncthreads();
        if (s + 1 < 8) STAGE(k0 + (s + 1) * 32, (s + 1) & 1)
        const int b = s & 1;
        f16x8 aH[2], bH[2];
#pragma unroll
        for (int mt = 0; mt < 2; ++mt) {
            const int row = wr * 32 + mt * 16 + c16;
            aH[mt] = *(const f16x8*)&Ahs[b][(q4 * 64 + row) * 8];
        }
#pragma unroll
        for (int nt = 0; nt < 2; ++nt) {
            const int col = wc * 32 + nt * 16 + c16;
            bH[nt] = *(const f16x8*)&Bhs[b][(q4 * 64 + col) * 8];
        }
#pragma unroll
        for (int mt = 0; mt < 2; ++mt)
#pragma unroll
            for (int nt = 0; nt < 2; ++nt)
                acc[mt][nt] = __builtin_amdgcn_mfma_f32_16x16x32_f16(aH[mt], bH[nt], acc[mt][nt], 0, 0, 0);
    }
#undef STAGE

#pragma unroll
    for (int mt = 0; mt < 2; ++mt)
#pragma unroll
        for (int nt = 0; nt < 2; ++nt)
#pragma unroll
            for (int j = 0; j < 4; ++j) {
                const int n_row = m0 + wr * 32 + mt * 16 + q4 * 4 + j;
                const int col = n0 + wc * 32 + nt * 16 + c16;
                const int b = n_row / SS, s2 = n_row % SS;
                const int h = col >> 6, e = col & 63;
                atomicAdd(&y[((b * HH + h) * SS + s2) * HD + e], acc[mt][nt][j]);
            }
}

// ---------------------------------------------------------------------------
// MFMA rank-3 attention (R13/R16 core) + FUSED output projection.
// Grid 512 = 16 bh x 32 qc (QCB=6) = 2 blocks/CU. 512 thr = 8 waves
// (2 lg x 4 kg). Core unchanged: K,L f16 frag-major LDS; B hoisted per q;
// v_exp_f32; 3 indep shuffle chains; rotated q order. NEW epilogue:
// attended (6x64) staged in attd LDS (rows 6..15 zero), then
// out[q, :] += attd . Wout[:, h*64:+64]^T via 16x16x64 MFMA pairs
// (8 waves x 4 j-tiles) + f32 global atomicAdd (8 head contribs/element).
// Removes the 48-block outproj kernel entirely.
// ---------------------------------------------------------------------------
__global__ __launch_bounds__(512, 4) void attn3d_mfma_kernel(
    const float* __restrict__ qh, const float* __restrict__ kh,
    const float* __restrict__ lh, const float* __restrict__ vh,
    const float* __restrict__ Wout, float* __restrict__ out) {
    __shared__ short Kf16[8][193][8];       // [ec][k(+pad)][8] f16: 24.7 KB
    __shared__ short Lf16[8][193][8];       // [ec][l(+pad)][8] f16: 24.7 KB
    __shared__ short qpk[QCB][8][8];        // [q][ec][8] f16: 768 B
    __shared__ float partial[2][QCB][196];  // [lg][q][k(+pad)]: 9.4 KB
    __shared__ float Wt[QCB][192];          // 4.6 KB
    __shared__ float attd[16][72];          // attended, rows 6..15 zero: 4.5 KB
    __shared__ float zinv[QCB];

    const int blk = blockIdx.x;
    const int bh = blk >> 5, qc = blk & 31;
    const int t = threadIdx.x;
    const int lane = t & 63, w = t >> 6;
    const int lg = w >> 2, kg = w & 3;
    const int c = lane & 15, eh = lane >> 4;

    // ---- stage q rows as f16 (scale+log2e folded) ----
    if (t < QCB * 64) {
        const int q = t >> 6, e = t & 63;
        const float v = qh[(bh * SS + qc * QCB + q) * HD + e] * SCL;
        qpk[q][e >> 3][e & 7] = __builtin_bit_cast(short, (_Float16)v);
    }
    // ---- stage K and L as f16 frag-major ----
#pragma unroll
    for (int j = 0; j < 3; ++j) {
        const int cid = t + 512 * j;          // 1536 8-elem chunks each
        const int k = cid >> 3, ec = cid & 7;
        float b8[8];
        const float* kp = &kh[(bh * SS + k) * HD + ec * 8];
        *(f32x4*)&b8[0] = *(const f32x4*)&kp[0];
        *(f32x4*)&b8[4] = *(const f32x4*)&kp[4];
        *(f16x8*)&Kf16[ec][k][0] = cvt8_f16_rne(b8);
        const float* lp = &lh[(bh * SS + k) * HD + ec * 8];
        *(f32x4*)&b8[0] = *(const f32x4*)&lp[0];
        *(f32x4*)&b8[4] = *(const f32x4*)&lp[4];
        *(f16x8*)&Lf16[ec][k][0] = cvt8_f16_rne(b8);
    }
    __syncthreads();   // qpk, Kf16, Lf16 ready

    // ---- runtime q loop, per-wave rotated phase; B hoisted per q ----
    for (int qi = 0; qi < QCB; ++qi) {
        const int q = (qi + w) % QCB;       // desync waves' phases
        const f16x8 qf0 = *(const f16x8*)&qpk[q][eh][0];
        const f16x8 qf1 = *(const f16x8*)&qpk[q][4 + eh][0];
        f16x8 Bf[3][2];
#pragma unroll
        for (int kt = 0; kt < 3; ++kt) {
            const int col = kg * 48 + kt * 16 + c;
            Bf[kt][0] = *(const f16x8*)&Kf16[eh][col][0] * qf0;
            Bf[kt][1] = *(const f16x8*)&Kf16[4 + eh][col][0] * qf1;
        }
        float rr0 = 0.f, rr1 = 0.f, rr2 = 0.f;
#pragma unroll
        for (int lt = 0; lt < 6; ++lt) {
            const int row = lg * 96 + lt * 16 + c;
            const f16x8 A0 = *(const f16x8*)&Lf16[eh][row][0];
            const f16x8 A1 = *(const f16x8*)&Lf16[4 + eh][row][0];
            f32x4 a0 = (f32x4){0.f, 0.f, 0.f, 0.f};
            f32x4 a1 = (f32x4){0.f, 0.f, 0.f, 0.f};
            f32x4 a2 = (f32x4){0.f, 0.f, 0.f, 0.f};
            a0 = __builtin_amdgcn_mfma_f32_16x16x32_f16(A0, Bf[0][0], a0, 0, 0, 0);
            a1 = __builtin_amdgcn_mfma_f32_16x16x32_f16(A0, Bf[1][0], a1, 0, 0, 0);
            a2 = __builtin_amdgcn_mfma_f32_16x16x32_f16(A0, Bf[2][0], a2, 0, 0, 0);
            a0 = __builtin_amdgcn_mfma_f32_16x16x32_f16(A1, Bf[0][1], a0, 0, 0, 0);
            a1 = __builtin_amdgcn_mfma_f32_16x16x32_f16(A1, Bf[1][1], a1, 0, 0, 0);
            a2 = __builtin_amdgcn_mfma_f32_16x16x32_f16(A1, Bf[2][1], a2, 0, 0, 0);
            rr0 += (__builtin_amdgcn_exp2f(a0[0]) + __builtin_amdgcn_exp2f(a0[1])) +
                   (__builtin_amdgcn_exp2f(a0[2]) + __builtin_amdgcn_exp2f(a0[3]));
            rr1 += (__builtin_amdgcn_exp2f(a1[0]) + __builtin_amdgcn_exp2f(a1[1])) +
                   (__builtin_amdgcn_exp2f(a1[2]) + __builtin_amdgcn_exp2f(a1[3]));
            rr2 += (__builtin_amdgcn_exp2f(a2[0]) + __builtin_amdgcn_exp2f(a2[1])) +
                   (__builtin_amdgcn_exp2f(a2[2]) + __builtin_amdgcn_exp2f(a2[3]));
        }
        rr0 += __shfl_xor(rr0, 16, 64);
        rr1 += __shfl_xor(rr1, 16, 64);
        rr2 += __shfl_xor(rr2, 16, 64);
        rr0 += __shfl_xor(rr0, 32, 64);
        rr1 += __shfl_xor(rr1, 32, 64);
        rr2 += __shfl_xor(rr2, 32, 64);
        if (eh == 0) {
            partial[lg][q][kg * 48 + 0 * 16 + c] = rr0;
            partial[lg][q][kg * 48 + 1 * 16 + c] = rr1;
            partial[lg][q][kg * 48 + 2 * 16 + c] = rr2;
        }
    }
    __syncthreads();   // all partials written

    // combine lg partials
    for (int id = t; id < QCB * 192; id += 512) {
        const int q = id / 192, k = id - q * 192;
        Wt[q][k] = partial[0][q][k] + partial[1][q][k];
    }
    // zero attd (incl. rows 6..15 used as zero A-rows in the epilogue MFMA)
    for (int id = t; id < 16 * 72; id += 512) ((float*)attd)[id] = 0.f;
    __syncthreads();

    // Z per q (wave w handles q = w)
    if (w < QCB) {
        const int q = w;
        float z = Wt[q][lane] + Wt[q][lane + 64] + Wt[q][lane + 128];
#pragma unroll
        for (int off = 32; off >= 1; off >>= 1) z += __shfl_xor(z, off, 64);
        if (lane == 0) zinv[q] = 1.f / z;
    }
    __syncthreads();

    // attended -> attd LDS: attd[q][d] = zinv * sum_k Wt[q][k] * vh[k,d]
    if (t < QCB * 64) {
        const int q = t >> 6, d = t & 63;
        const float* vp = vh + bh * SS * HD + d;
        float sum = 0.f;
        for (int k0 = 0; k0 < SS; k0 += 8) {
            float v8[8];
#pragma unroll
            for (int j = 0; j < 8; ++j) v8[j] = vp[(k0 + j) * HD];
#pragma unroll
            for (int j = 0; j < 8; ++j) sum = fmaf(Wt[q][k0 + j], v8[j], sum);
        }
        attd[q][d] = sum * zinv[q];
    }
    __syncthreads();

    // ---- fused output projection: out[q,:] += attd . Wout[:, h*64:+64]^T ----
    // A = attd (16 rows, 6 valid, K=64); B[k][col=j] = Wout[j, h*64+k].
    // Wave w handles j-tiles w*4 .. w*4+3 (32 tiles x 16 = 512 cols).
    const int b = bh >> 3, h = bh & 7;
    f16x8 Ae0, Ae1;
    {
        float a8[8];
        *(f32x4*)&a8[0] = *(const f32x4*)&attd[c][eh * 8];
        *(f32x4*)&a8[4] = *(const f32x4*)&attd[c][eh * 8 + 4];
        Ae0 = cvt8_f16_rne(a8);
        *(f32x4*)&a8[0] = *(const f32x4*)&attd[c][32 + eh * 8];
        *(f32x4*)&a8[4] = *(const f32x4*)&attd[c][32 + eh * 8 + 4];
        Ae1 = cvt8_f16_rne(a8);
    }
#pragma unroll
    for (int jt = 0; jt < 4; ++jt) {
        const int j = (w * 4 + jt) * 16 + c;
        const float* wp = &Wout[j * DD + h * HD];
        float b8[8];
        *(f32x4*)&b8[0] = *(const f32x4*)&wp[eh * 8];
        *(f32x4*)&b8[4] = *(const f32x4*)&wp[eh * 8 + 4];
        const f16x8 B0 = cvt8_f16_rne(b8);
        *(f32x4*)&b8[0] = *(const f32x4*)&wp[32 + eh * 8];
        *(f32x4*)&b8[4] = *(const f32x4*)&wp[32 + eh * 8 + 4];
        const f16x8 B1 = cvt8_f16_rne(b8);
        f32x4 oc = (f32x4){0.f, 0.f, 0.f, 0.f};
        oc = __builtin_amdgcn_mfma_f32_16x16x32_f16(Ae0, B0, oc, 0, 0, 0);
        oc = __builtin_amdgcn_mfma_f32_16x16x32_f16(Ae1, B1, oc, 0, 0, 0);
        // C layout: row q = eh*4+jj (valid < 6), col = c
#pragma unroll
        for (int jj = 0; jj < 4; ++jj) {
            const int q = eh * 4 + jj;
            if (q < QCB)
                atomicAdd(&out[(b * SS + qc * QCB + q) * DD + (w * 4 + jt) * 16 + c], oc[jj]);
        }
    }
}

extern "C" void kernel_launch(void* const* d_in, const int* in_sizes, int n_in,
                              void* d_out, int out_size, void* d_ws, size_t ws_size,
                              hipStream_t stream) {
    (void)in_sizes; (void)n_in; (void)out_size; (void)ws_size;
    const float* q    = (const float*)d_in[0];
    const float* k    = (const float*)d_in[1];
    const float* l    = (const float*)d_in[2];
    const float* v    = (const float*)d_in[3];
    const float* Wq   = (const float*)d_in[4];
    const float* Wk   = (const float*)d_in[5];
    const float* Wv   = (const float*)d_in[6];
    const float* Wout = (const float*)d_in[7];
    float* out = (float*)d_out;

    float* ws  = (float*)d_ws;
    float* qhp = ws + 0 * PROJ_N;
    float* khp = ws + 1 * PROJ_N;
    float* lhp = ws + 2 * PROJ_N;
    float* vhp = ws + 3 * PROJ_N;

    // zero atomic targets (ws proj region + out)
    zero_kernel<<<dim3((4 * PROJ_N + 255) / 256), 256, 0, stream>>>(ws, out);
    // 4 projections, split-K x2 (384 blocks)
    proj4_kernel<<<dim3(384 / 64, 512 / 64, 8), 256, 0, stream>>>(
        q, k, l, v, Wq, Wk, Wv, ws);
    // rank-3 attention + fused output projection
    attn3d_mfma_kernel<<<dim3(16 * NQC), 512, 0, stream>>>(qhp, khp, lhp, vhp, Wout, out);
}